// Round 3
// baseline (209.590 us; speedup 1.0000x reference)
//
#include <hip/hip_runtime.h>
#include <math.h>

// MinkowskiInstanceNorm: segment instance-norm, N rows x C=32 channels, S segments.
// ws layout (floats): SUM[64*32] @0, SUMSQ @2048, SCALE @4096, SHIFT @6144.

#define WS_SUM   0
#define WS_SUMSQ 2048
#define WS_SCALE 4096
#define WS_SHIFT 6144

__global__ void zero_ws_kernel(float* __restrict__ ws) {
    int t = blockIdx.x * blockDim.x + threadIdx.x;
    if (t < 4096) ws[t] = 0.0f;   // zero SUM + SUMSQ regions
}

#define ACC4(A, Q, V)                                        \
    do {                                                     \
        (A).x += (V).x; (A).y += (V).y;                      \
        (A).z += (V).z; (A).w += (V).w;                      \
        (Q).x += (V).x * (V).x; (Q).y += (V).y * (V).y;      \
        (Q).z += (V).z * (V).z; (Q).w += (V).w * (V).w;      \
    } while (0)

// Block b handles contiguous rows [b*chunk, min(N,(b+1)*chunk)).
// thread t: cg = t&7 (which float4 of the row), rl = t>>3 (row offset mod 32).
// seg_ids sorted -> almost all blocks span ONE segment: branch-free fast path.
__global__ __launch_bounds__(256) void reduce_kernel(
        const float4* __restrict__ feats4, const int* __restrict__ seg,
        float* __restrict__ ws, int N, int chunk) {
    __shared__ float4 s_sum[256];
    __shared__ float4 s_sq[256];
    float* sum_g   = ws + WS_SUM;
    float* sumsq_g = ws + WS_SUMSQ;

    int t  = threadIdx.x;
    int cg = t & 7;
    int rl = t >> 3;
    int bstart = blockIdx.x * chunk;
    if (bstart >= N) return;                  // uniform across block
    int bend = min(N, bstart + chunk);

    int seg_first = seg[bstart];
    int seg_last  = seg[bend - 1];

    if (seg_first == seg_last) {
        // ---- fast path: one segment, no inner seg[] reads, unroll x4 ----
        float4 a0 = make_float4(0.f, 0.f, 0.f, 0.f), a1 = a0;
        float4 q0 = a0, q1 = a0;
        int r = bstart + rl;
        for (; r < bend - 96; r += 128) {
            float4 v0 = feats4[(r      ) * 8 + cg];
            float4 v1 = feats4[(r + 32) * 8 + cg];
            float4 v2 = feats4[(r + 64) * 8 + cg];
            float4 v3 = feats4[(r + 96) * 8 + cg];
            ACC4(a0, q0, v0);
            ACC4(a1, q1, v1);
            ACC4(a0, q0, v2);
            ACC4(a1, q1, v3);
        }
        for (; r < bend; r += 32) {
            float4 v = feats4[r * 8 + cg];
            ACC4(a0, q0, v);
        }
        a0.x += a1.x; a0.y += a1.y; a0.z += a1.z; a0.w += a1.w;
        q0.x += q1.x; q0.y += q1.y; q0.z += q1.z; q0.w += q1.w;
        s_sum[t] = a0;
        s_sq[t]  = q0;
        __syncthreads();
        for (int off = 128; off >= 8; off >>= 1) {
            if (t < off) {
                float4 a = s_sum[t + off], b = s_sq[t + off];
                s_sum[t].x += a.x; s_sum[t].y += a.y;
                s_sum[t].z += a.z; s_sum[t].w += a.w;
                s_sq[t].x  += b.x; s_sq[t].y  += b.y;
                s_sq[t].z  += b.z; s_sq[t].w  += b.w;
            }
            __syncthreads();
        }
        if (t < 8) {
            float4 a = s_sum[t], b = s_sq[t];
            int base = seg_first * 32 + t * 4;
            atomicAdd(&sum_g[base + 0], a.x);
            atomicAdd(&sum_g[base + 1], a.y);
            atomicAdd(&sum_g[base + 2], a.z);
            atomicAdd(&sum_g[base + 3], a.w);
            atomicAdd(&sumsq_g[base + 0], b.x);
            atomicAdd(&sumsq_g[base + 1], b.y);
            atomicAdd(&sumsq_g[base + 2], b.z);
            atomicAdd(&sumsq_g[base + 3], b.w);
        }
        return;
    }

    // ---- general path: block straddles a segment boundary (<=7 blocks) ----
    for (int s = seg_first; s <= seg_last; ++s) {
        float4 acc  = make_float4(0.f, 0.f, 0.f, 0.f);
        float4 accq = make_float4(0.f, 0.f, 0.f, 0.f);
        for (int r = bstart + rl; r < bend; r += 32) {
            if (seg[r] == s) {
                float4 v = feats4[r * 8 + cg];
                ACC4(acc, accq, v);
            }
        }
        s_sum[t] = acc;
        s_sq[t]  = accq;
        __syncthreads();
        for (int off = 128; off >= 8; off >>= 1) {
            if (t < off) {
                float4 a = s_sum[t + off], b = s_sq[t + off];
                s_sum[t].x += a.x; s_sum[t].y += a.y;
                s_sum[t].z += a.z; s_sum[t].w += a.w;
                s_sq[t].x  += b.x; s_sq[t].y  += b.y;
                s_sq[t].z  += b.z; s_sq[t].w  += b.w;
            }
            __syncthreads();
        }
        if (t < 8) {
            float4 a = s_sum[t], b = s_sq[t];
            int base = s * 32 + t * 4;
            atomicAdd(&sum_g[base + 0], a.x);
            atomicAdd(&sum_g[base + 1], a.y);
            atomicAdd(&sum_g[base + 2], a.z);
            atomicAdd(&sum_g[base + 3], a.w);
            atomicAdd(&sumsq_g[base + 0], b.x);
            atomicAdd(&sumsq_g[base + 1], b.y);
            atomicAdd(&sumsq_g[base + 2], b.z);
            atomicAdd(&sumsq_g[base + 3], b.w);
        }
        __syncthreads();
    }
}

__device__ inline int lower_bound(const int* __restrict__ a, int n, int key) {
    int lo = 0, hi = n;
    while (lo < hi) {
        int mid = (lo + hi) >> 1;
        if (a[mid] < key) lo = mid + 1; else hi = mid;
    }
    return lo;
}

__global__ void stats_kernel(const int* __restrict__ seg,
                             const float* __restrict__ w,
                             const float* __restrict__ b,
                             const int* __restrict__ nsp,
                             float* __restrict__ ws, int N) {
    __shared__ int s_cnt[64];
    const float* sum_g   = ws + WS_SUM;
    const float* sumsq_g = ws + WS_SUMSQ;
    float* scale_g = ws + WS_SCALE;
    float* shift_g = ws + WS_SHIFT;

    int t  = threadIdx.x;
    int ns = *nsp;
    for (int s = t; s < ns; s += blockDim.x)
        s_cnt[s] = lower_bound(seg, N, s + 1) - lower_bound(seg, N, s);
    __syncthreads();

    for (int i = t; i < ns * 32; i += blockDim.x) {
        int s = i >> 5, c = i & 31;
        float cnt  = fmaxf((float)s_cnt[s], 1.0f);
        float mean = sum_g[i] / cnt;
        float var  = fmaxf(sumsq_g[i] / cnt - mean * mean, 0.0f);
        float inv  = rsqrtf(var + 1e-8f);
        float sc   = inv * w[c];
        scale_g[i] = sc;
        shift_g[i] = b[c] - mean * sc;
    }
}

__global__ __launch_bounds__(256) void apply_kernel(
        const float4* __restrict__ feats4, const int* __restrict__ seg,
        const float* __restrict__ ws, float4* __restrict__ out4, int total4) {
    const float4* scale4 = (const float4*)(ws + WS_SCALE);
    const float4* shift4 = (const float4*)(ws + WS_SHIFT);
    int stride = gridDim.x * blockDim.x;
    for (int i = blockIdx.x * blockDim.x + threadIdx.x; i < total4; i += stride) {
        int row = i >> 3, cg = i & 7;
        int s = seg[row];
        float4 v  = feats4[i];
        float4 sc = scale4[s * 8 + cg];
        float4 sh = shift4[s * 8 + cg];
        float4 o;
        o.x = fmaf(v.x, sc.x, sh.x);
        o.y = fmaf(v.y, sc.y, sh.y);
        o.z = fmaf(v.z, sc.z, sh.z);
        o.w = fmaf(v.w, sc.w, sh.w);
        out4[i] = o;
    }
}

extern "C" void kernel_launch(void* const* d_in, const int* in_sizes, int n_in,
                              void* d_out, int out_size, void* d_ws, size_t ws_size,
                              hipStream_t stream) {
    const float* feats = (const float*)d_in[0];
    const int*   seg   = (const int*)d_in[1];
    const float* w     = (const float*)d_in[2];
    const float* b     = (const float*)d_in[3];
    const int*   nsp   = (const int*)d_in[4];
    float* out = (float*)d_out;
    float* ws  = (float*)d_ws;

    int N = in_sizes[1];               // number of rows (seg_ids length)
    int total4 = N * 8;                // N * 32 channels / 4 per float4

    const int NB = 2048;
    int chunk = (N + NB - 1) / NB;

    hipLaunchKernelGGL(zero_ws_kernel, dim3(16), dim3(256), 0, stream, ws);
    hipLaunchKernelGGL(reduce_kernel, dim3(NB), dim3(256), 0, stream,
                       (const float4*)feats, seg, ws, N, chunk);
    hipLaunchKernelGGL(stats_kernel, dim3(1), dim3(256), 0, stream,
                       seg, w, b, nsp, ws, N);
    hipLaunchKernelGGL(apply_kernel, dim3(4096), dim3(256), 0, stream,
                       (const float4*)feats, seg, ws, (float4*)out, total4);
}

// Round 4
// 174.567 us; speedup vs baseline: 1.2006x; 1.2006x over previous
//
#include <hip/hip_runtime.h>
#include <math.h>

// MinkowskiInstanceNorm: segment instance-norm, N rows x C=32 channels, S segments (sorted seg_ids).
// ws layout (floats): SUM[64*32] @0, SUMSQ @2048, CNT[64] @4096, SCALE @4352, SHIFT @6400.

#define WS_SUM   0
#define WS_SUMSQ 2048
#define WS_CNT   4096
#define WS_SCALE 4352
#define WS_SHIFT 6400

typedef float f32x4 __attribute__((ext_vector_type(4)));

__global__ void zero_ws_kernel(float* __restrict__ ws) {
    int t = blockIdx.x * blockDim.x + threadIdx.x;
    if (t < 4352) ws[t] = 0.0f;   // zero SUM + SUMSQ + CNT
}

#define ACC4(A, Q, V)                                        \
    do {                                                     \
        (A).x += (V).x; (A).y += (V).y;                      \
        (A).z += (V).z; (A).w += (V).w;                      \
        (Q).x += (V).x * (V).x; (Q).y += (V).y * (V).y;      \
        (Q).z += (V).z * (V).z; (Q).w += (V).w * (V).w;      \
    } while (0)

#define ADD4(A, B)                                           \
    do {                                                     \
        (A).x += (B).x; (A).y += (B).y;                      \
        (A).z += (B).z; (A).w += (B).w;                      \
    } while (0)

// Block b handles contiguous rows [b*chunk, min(N,(b+1)*chunk)).
// thread t: cg = t&7 (float4 index in row), rl = t>>3 (row offset mod 32).
__global__ __launch_bounds__(256) void reduce_kernel(
        const float4* __restrict__ feats4, const int* __restrict__ seg,
        float* __restrict__ ws, int N, int chunk) {
    __shared__ float4 s_sum[256];
    __shared__ float4 s_sq[256];
    __shared__ int    s_c[256];
    float* sum_g   = ws + WS_SUM;
    float* sumsq_g = ws + WS_SUMSQ;
    float* cnt_g   = ws + WS_CNT;

    int t  = threadIdx.x;
    int cg = t & 7;
    int rl = t >> 3;
    int bstart = blockIdx.x * chunk;
    if (bstart >= N) return;                  // uniform across block
    int bend = min(N, bstart + chunk);
    int rows = bend - bstart;

    int seg_first = seg[bstart];
    int seg_last  = seg[bend - 1];

    if (seg_first == seg_last) {
        // ---- fast path: single segment, 8 independent load streams ----
        float4 a0 = make_float4(0.f,0.f,0.f,0.f), a1 = a0, a2 = a0, a3 = a0;
        float4 q0 = a0, q1 = a0, q2 = a0, q3 = a0;
        const float4* p = feats4 + (size_t)(bstart + rl) * 8 + cg;
        int r = rl;
        for (; r + 224 < rows; r += 256) {     // 8 rows-of-32 per iter
            float4 v0 = p[0 * 256];
            float4 v1 = p[1 * 256];
            float4 v2 = p[2 * 256];
            float4 v3 = p[3 * 256];
            float4 v4 = p[4 * 256];
            float4 v5 = p[5 * 256];
            float4 v6 = p[6 * 256];
            float4 v7 = p[7 * 256];
            ACC4(a0, q0, v0);
            ACC4(a1, q1, v1);
            ACC4(a2, q2, v2);
            ACC4(a3, q3, v3);
            ACC4(a0, q0, v4);
            ACC4(a1, q1, v5);
            ACC4(a2, q2, v6);
            ACC4(a3, q3, v7);
            p += 8 * 256;
        }
        for (; r < rows; r += 32) {
            float4 v = *p;
            ACC4(a0, q0, v);
            p += 256;
        }
        ADD4(a0, a1); ADD4(a2, a3); ADD4(a0, a2);
        ADD4(q0, q1); ADD4(q2, q3); ADD4(q0, q2);
        s_sum[t] = a0;
        s_sq[t]  = q0;
        __syncthreads();
        for (int off = 128; off >= 8; off >>= 1) {
            if (t < off) {
                float4 a = s_sum[t + off], b = s_sq[t + off];
                ADD4(s_sum[t], a);
                ADD4(s_sq[t], b);
            }
            __syncthreads();
        }
        if (t < 8) {
            float4 a = s_sum[t], b = s_sq[t];
            int base = seg_first * 32 + t * 4;
            atomicAdd(&sum_g[base + 0], a.x);
            atomicAdd(&sum_g[base + 1], a.y);
            atomicAdd(&sum_g[base + 2], a.z);
            atomicAdd(&sum_g[base + 3], a.w);
            atomicAdd(&sumsq_g[base + 0], b.x);
            atomicAdd(&sumsq_g[base + 1], b.y);
            atomicAdd(&sumsq_g[base + 2], b.z);
            atomicAdd(&sumsq_g[base + 3], b.w);
        }
        if (t == 0) atomicAdd(&cnt_g[seg_first], (float)rows);
        return;
    }

    // ---- general path: block straddles a segment boundary (rare) ----
    for (int s = seg_first; s <= seg_last; ++s) {
        float4 acc  = make_float4(0.f, 0.f, 0.f, 0.f);
        float4 accq = make_float4(0.f, 0.f, 0.f, 0.f);
        int c = 0;
        for (int r = bstart + rl; r < bend; r += 32) {
            if (seg[r] == s) {
                float4 v = feats4[(size_t)r * 8 + cg];
                ACC4(acc, accq, v);
                c++;
            }
        }
        s_sum[t] = acc;
        s_sq[t]  = accq;
        s_c[t]   = (cg == 0) ? c : 0;
        __syncthreads();
        for (int off = 128; off >= 8; off >>= 1) {
            if (t < off) {
                float4 a = s_sum[t + off], b = s_sq[t + off];
                ADD4(s_sum[t], a);
                ADD4(s_sq[t], b);
                s_c[t] += s_c[t + off];
            }
            __syncthreads();
        }
        if (t < 8) {
            float4 a = s_sum[t], b = s_sq[t];
            int base = s * 32 + t * 4;
            atomicAdd(&sum_g[base + 0], a.x);
            atomicAdd(&sum_g[base + 1], a.y);
            atomicAdd(&sum_g[base + 2], a.z);
            atomicAdd(&sum_g[base + 3], a.w);
            atomicAdd(&sumsq_g[base + 0], b.x);
            atomicAdd(&sumsq_g[base + 1], b.y);
            atomicAdd(&sumsq_g[base + 2], b.z);
            atomicAdd(&sumsq_g[base + 3], b.w);
        }
        if (t == 0) {
            int ctot = s_c[0] + s_c[1] + s_c[2] + s_c[3]
                     + s_c[4] + s_c[5] + s_c[6] + s_c[7];
            atomicAdd(&cnt_g[s], (float)ctot);
        }
        __syncthreads();
    }
}

__global__ void stats_kernel(const float* __restrict__ w,
                             const float* __restrict__ b,
                             const int* __restrict__ nsp,
                             float* __restrict__ ws) {
    const float* sum_g   = ws + WS_SUM;
    const float* sumsq_g = ws + WS_SUMSQ;
    const float* cnt_g   = ws + WS_CNT;
    float* scale_g = ws + WS_SCALE;
    float* shift_g = ws + WS_SHIFT;

    int t  = threadIdx.x;
    int ns = *nsp;
    for (int i = t; i < ns * 32; i += blockDim.x) {
        int s = i >> 5, c = i & 31;
        float cnt  = fmaxf(cnt_g[s], 1.0f);
        float mean = sum_g[i] / cnt;
        float var  = fmaxf(sumsq_g[i] / cnt - mean * mean, 0.0f);
        float inv  = rsqrtf(var + 1e-8f);
        float sc   = inv * w[c];
        scale_g[i] = sc;
        shift_g[i] = b[c] - mean * sc;
    }
}

__global__ __launch_bounds__(256) void apply_kernel(
        const float* __restrict__ feats, const int* __restrict__ seg,
        const float* __restrict__ ws, float* __restrict__ out, int total4) {
    const f32x4* f4 = (const f32x4*)feats;
    f32x4*       o4 = (f32x4*)out;
    const f32x4* scale4 = (const f32x4*)(ws + WS_SCALE);
    const f32x4* shift4 = (const f32x4*)(ws + WS_SHIFT);
    int stride = gridDim.x * blockDim.x;
    for (int i = blockIdx.x * blockDim.x + threadIdx.x; i < total4; i += stride) {
        int row = i >> 3, cg = i & 7;
        int s = seg[row];
        f32x4 v  = __builtin_nontemporal_load(&f4[i]);  // last use of feats
        f32x4 sc = scale4[s * 8 + cg];
        f32x4 sh = shift4[s * 8 + cg];
        f32x4 o;
        o.x = fmaf(v.x, sc.x, sh.x);
        o.y = fmaf(v.y, sc.y, sh.y);
        o.z = fmaf(v.z, sc.z, sh.z);
        o.w = fmaf(v.w, sc.w, sh.w);
        __builtin_nontemporal_store(o, &o4[i]);         // don't evict feats from L3
    }
}

extern "C" void kernel_launch(void* const* d_in, const int* in_sizes, int n_in,
                              void* d_out, int out_size, void* d_ws, size_t ws_size,
                              hipStream_t stream) {
    const float* feats = (const float*)d_in[0];
    const int*   seg   = (const int*)d_in[1];
    const float* w     = (const float*)d_in[2];
    const float* b     = (const float*)d_in[3];
    const int*   nsp   = (const int*)d_in[4];
    float* out = (float*)d_out;
    float* ws  = (float*)d_ws;

    int N = in_sizes[1];               // number of rows (seg_ids length)
    int total4 = N * 8;                // N * 32 channels / 4 per float4

    const int NB = 2048;
    int chunk = (N + NB - 1) / NB;

    hipLaunchKernelGGL(zero_ws_kernel, dim3(17), dim3(256), 0, stream, ws);
    hipLaunchKernelGGL(reduce_kernel, dim3(NB), dim3(256), 0, stream,
                       (const float4*)feats, seg, ws, N, chunk);
    hipLaunchKernelGGL(stats_kernel, dim3(1), dim3(256), 0, stream,
                       w, b, nsp, ws);
    hipLaunchKernelGGL(apply_kernel, dim3(4096), dim3(256), 0, stream,
                       feats, seg, ws, out, total4);
}